// Round 2
// baseline (374.917 us; speedup 1.0000x reference)
//
#include <hip/hip_runtime.h>
#include <hip/hip_bf16.h>

// Mlp_moe: patch MLP + 6-class 2-route MoE on cls tokens.
// Round 2: big GEMMs moved to 256x256 8-phase counted-vmcnt structure (T2+T3+T4+T5).

typedef __bf16 bf16x8 __attribute__((ext_vector_type(8)));
typedef float f32x4 __attribute__((ext_vector_type(4)));
typedef unsigned short u16;

#define DEVINL __device__ __forceinline__

DEVINL u16 f2bf(float f) {
  unsigned int u = __builtin_bit_cast(unsigned int, f);
  u += 0x7FFFu + ((u >> 16) & 1u);
  return (u16)(u >> 16);
}

DEVINL float gelu_exact(float v) {
  return 0.5f * v * (1.0f + erff(v * 0.70710678118654752440f));
}

DEVINL void async_load16(const void* g, void* l) {
  __builtin_amdgcn_global_load_lds(
      (const __attribute__((address_space(1))) unsigned int*)g,
      (__attribute__((address_space(3))) unsigned int*)l, 16, 0, 0);
}

DEVINL void barrier_np() {  // raw barrier, no vmcnt drain; fences stop IR reordering
  asm volatile("" ::: "memory");
  __builtin_amdgcn_s_barrier();
  asm volatile("" ::: "memory");
}
DEVINL void vmwait6() { asm volatile("s_waitcnt vmcnt(6)" ::: "memory"); }

// ---------------- conversion kernels ----------------
__global__ void cvt_bf16(const float* __restrict__ in, u16* __restrict__ out, int n) {
  const int i = (blockIdx.x * 256 + threadIdx.x) * 4;
  if (i >= n) return;
  const float4 v = *(const float4*)(in + i);
  ushort4 u;
  u.x = f2bf(v.x); u.y = f2bf(v.y); u.z = f2bf(v.z); u.w = f2bf(v.w);
  *(ushort4*)(out + i) = u;
}

// fused 4-region f32->bf16 (fc1_w, fc2_w, atom_in_w, atom_out_w)
__global__ void cvt4(const float* __restrict__ s0, u16* __restrict__ d0,
                     const float* __restrict__ s1, u16* __restrict__ d1,
                     const float* __restrict__ s2, u16* __restrict__ d2,
                     const float* __restrict__ s3, u16* __restrict__ d3) {
  // region block counts: 2304, 2304, 11520, 11520 (1024 elems per block)
  int b = blockIdx.x;
  const float* s; u16* d;
  if (b < 2304) { s = s0; d = d0; }
  else if (b < 4608) { s = s1; d = d1; b -= 2304; }
  else if (b < 16128) { s = s2; d = d2; b -= 4608; }
  else { s = s3; d = d3; b -= 16128; }
  const int i = (b * 256 + threadIdx.x) * 4;
  const float4 v = *(const float4*)(s + i);
  ushort4 u;
  u.x = f2bf(v.x); u.y = f2bf(v.y); u.z = f2bf(v.z); u.w = f2bf(v.w);
  *(ushort4*)(d + i) = u;
}

// split x (64,203,768) into cls (64*6,768) and patch (64*197,768), bf16
__global__ void cvt_x(const float* __restrict__ x, u16* __restrict__ xc, u16* __restrict__ xp) {
  const int e = (blockIdx.x * 256 + threadIdx.x) * 4;
  const int t = e / 768, d = e % 768;
  const int b = t / 203, i = t % 203;
  const float4 v = *(const float4*)(x + e);
  ushort4 u;
  u.x = f2bf(v.x); u.y = f2bf(v.y); u.z = f2bf(v.z); u.w = f2bf(v.w);
  if (i < 6) *(ushort4*)(xc + (size_t)(b * 6 + i) * 768 + d) = u;
  else       *(ushort4*)(xp + (size_t)(b * 197 + (i - 6)) * 768 + d) = u;
}

// ---------------- gate / routing decision (fp64 accum) ----------------
__global__ void gate_kernel(const float* __restrict__ x,
                            const float* __restrict__ gate_pair,
                            const float* __restrict__ balance_bias,
                            int* __restrict__ rstar, float* __restrict__ wstar) {
  const int lane = threadIdx.x & 63, wid = threadIdx.x >> 6;
  const int idx = blockIdx.x * 4 + wid;
  const int b = idx / 6, n = idx % 6;
  const float* xv = x + (size_t)(b * 203 + n) * 768;
  const float* w0 = gate_pair + (size_t)(n * 2 + 0) * 768;
  const float* w1 = gate_pair + (size_t)(n * 2 + 1) * 768;
  double xx = 0, a00 = 0, a11 = 0, d0 = 0, d1 = 0;
  for (int d = lane; d < 768; d += 64) {
    double xd = xv[d], g0 = w0[d], g1 = w1[d];
    xx += xd * xd; a00 += g0 * g0; a11 += g1 * g1; d0 += xd * g0; d1 += xd * g1;
  }
#pragma unroll
  for (int off = 32; off; off >>= 1) {
    xx  += __shfl_xor(xx, off);
    a00 += __shfl_xor(a00, off);
    a11 += __shfl_xor(a11, off);
    d0  += __shfl_xor(d0, off);
    d1  += __shfl_xor(d1, off);
  }
  if (lane == 0) {
    double nx = fmax(sqrt(xx), 1e-12), n0 = fmax(sqrt(a00), 1e-12), n1 = fmax(sqrt(a11), 1e-12);
    double l0 = d0 / (nx * n0) + (double)balance_bias[n * 2 + 0];
    double l1 = d1 / (nx * n1) + (double)balance_bias[n * 2 + 1];
    const int r = (l1 > l0) ? 1 : 0;
    double m = fmax(l0, l1);
    double e0 = exp(l0 - m), e1 = exp(l1 - m);
    rstar[idx] = r;
    wstar[idx] = (float)(((r == 1) ? e1 : e0) / (e0 + e1));
  }
}

// ---------------- 256x256 8-phase GEMM: C = A(MxK) * B(NxK)^T + bias ----------------
// 512 thr = 8 waves (2M x 4N), per-wave 128x64 out, BK=64 split in two k-halves.
// Half-tile = 256 rows x 32 k (16 KB, 2 global_load_lds/thread). Issue 5 phases ahead,
// vmcnt(6) at q1/q3 ends => halves needed at q0/q2 provably landed (3 half-tiles in flight).
// LDS layout per buf: [A-k0][B-k0][A-k1][B-k1] @16KB each; slot swizzle sl^=( (row>>1)&3 ).
#define MFMA_BF16 __builtin_amdgcn_mfma_f32_16x16x32_bf16
#define MMA_HALF(NLO)                                                   \
  do {                                                                  \
    __builtin_amdgcn_s_setprio(1);                                      \
    _Pragma("unroll") for (int im = 0; im < 8; ++im) {                  \
      acc[im][NLO] = MFMA_BF16(af[im], bfv[0], acc[im][NLO], 0, 0, 0);  \
      acc[im][NLO + 1] = MFMA_BF16(af[im], bfv[1], acc[im][NLO + 1], 0, 0, 0); \
    }                                                                   \
    __builtin_amdgcn_s_setprio(0);                                      \
  } while (0)

template <int EPI>
__global__ __launch_bounds__(512, 2) void gemm8(
    const u16* __restrict__ A, const u16* __restrict__ B,
    const float* __restrict__ bias, void* __restrict__ Cout,
    int M, int K, int ldc) {
  __shared__ char lds[131072];
  const int tid = threadIdx.x;
  const int lane = tid & 63, wid = tid >> 6;
  const int wr = wid >> 2, wc = wid & 3;
  const int tm = blockIdx.y * 256, tn = blockIdx.x * 256;
  const int ksteps = K >> 6;
  const int HMAX = ksteps * 4;

  auto stage = [&](int h) {
    if (h >= HMAX) return;
    const int T = h >> 2, Q = h & 3;
    const int kcol = T * 64 + (Q >> 1) * 32;
    char* base = lds + (T & 1) * 65536 + Q * 16384 + wid * 1024;
    const u16* Mat = (Q & 1) ? B : A;
    const int rb = (Q & 1) ? tn : tm;
#pragma unroll
    for (int j = 0; j < 2; ++j) {
      const int r = j * 128 + (tid >> 2);
      const int sl = (tid & 3) ^ ((r >> 1) & 3);
      int gr = rb + r;
      if (!(Q & 1)) gr = gr < M ? gr : M - 1;  // clamp A rows (tail tile)
      async_load16(Mat + (size_t)gr * K + kcol + sl * 8, base + j * 8192);
    }
  };
  auto lda = [&](int buf, int kh, bf16x8* af) {
    const char* base = lds + buf * 65536 + kh * 32768;
    const int ksl = lane >> 4;
#pragma unroll
    for (int im = 0; im < 8; ++im) {
      const int row = wr * 128 + im * 16 + (lane & 15);
      const int sl = ksl ^ ((row >> 1) & 3);
      af[im] = *(const bf16x8*)(base + row * 64 + sl * 16);
    }
  };
  auto ldb = [&](int buf, int kh, int nlo, bf16x8* bfv) {
    const char* base = lds + buf * 65536 + kh * 32768 + 16384;
    const int ksl = lane >> 4;
#pragma unroll
    for (int q = 0; q < 2; ++q) {
      const int row = wc * 64 + (nlo + q) * 16 + (lane & 15);
      const int sl = ksl ^ ((row >> 1) & 3);
      bfv[q] = *(const bf16x8*)(base + row * 64 + sl * 16);
    }
  };

  f32x4 acc[8][4] = {};
  bf16x8 af[8], bfv[2];

  // prologue: halves h=0..4 (tile0 complete + A-k0 of tile1); h=0,1 must land
  for (int h = 0; h < 5 && h < HMAX; ++h) stage(h);
  vmwait6();
  barrier_np();

  for (int t = 0; t < ksteps; ++t) {
    const int buf = t & 1;
    const int p = 4 * t;
    // q0: ks0, n0-1
    lda(buf, 0, af);
    ldb(buf, 0, 0, bfv);
    stage(p + 5);
    barrier_np();
    MMA_HALF(0);
    barrier_np();
    // q1: ks0, n2-3
    ldb(buf, 0, 2, bfv);
    stage(p + 6);
    barrier_np();
    MMA_HALF(2);
    vmwait6();
    barrier_np();
    // q2: ks1, n0-1
    lda(buf, 1, af);
    ldb(buf, 1, 0, bfv);
    stage(p + 7);
    barrier_np();
    MMA_HALF(0);
    barrier_np();
    // q3: ks1, n2-3
    ldb(buf, 1, 2, bfv);
    stage(p + 8);
    barrier_np();
    MMA_HALF(2);
    vmwait6();
    barrier_np();
  }

  const int cn = lane & 15, cr4 = (lane >> 4) * 4;
#pragma unroll
  for (int im = 0; im < 8; ++im)
#pragma unroll
    for (int in_ = 0; in_ < 4; ++in_) {
      const int col = tn + wc * 64 + in_ * 16 + cn;
      const float bv = bias[col];
#pragma unroll
      for (int j = 0; j < 4; ++j) {
        const int row = tm + wr * 128 + im * 16 + cr4 + j;
        if (row < M) {
          const float v = acc[im][in_][j] + bv;
          if (EPI == 0) {
            ((u16*)Cout)[(size_t)row * ldc + col] = f2bf(gelu_exact(v));
          } else {
            const int b = row / 197, pp = row % 197;
            ((float*)Cout)[((size_t)(b * 203 + 6 + pp)) * 768 + col] = v;
          }
        }
      }
    }
}

// ---------------- 128x128 m97-structure GEMM (kept for the small hid_all GEMM) ----------------
template <int EPI>
__global__ __launch_bounds__(256, 2) void gemm_bt(
    const u16* __restrict__ A, const u16* __restrict__ B,
    const float* __restrict__ bias, void* __restrict__ Cout,
    int M, int K, int ldc) {
  __shared__ u16 As[128 * 64];
  __shared__ u16 Bs[128 * 64];
  const int lane = threadIdx.x & 63;
  const int wid  = threadIdx.x >> 6;
  const int wr   = wid >> 1, wc = wid & 1;
  const int tm   = blockIdx.y * 128;
  const int tn   = blockIdx.x * 128;

  f32x4 acc[4][4] = {};
  const int rA = lane >> 3;
  const int sA = lane & 7;

  const int ksteps = K >> 6;
  for (int ks = 0; ks < ksteps; ++ks) {
    const int k0 = ks << 6;
#pragma unroll
    for (int c = 0; c < 4; ++c) {
      const int chunk = wid * 4 + c;
      const int row   = chunk * 8 + rA;
      int grow = tm + row;
      grow = grow < M ? grow : (M - 1);
      const int slot = sA ^ (row & 7);
      async_load16(A + (size_t)grow * K + k0 + slot * 8, (char*)As + chunk * 1024);
    }
#pragma unroll
    for (int c = 0; c < 4; ++c) {
      const int chunk = wid * 4 + c;
      const int row   = chunk * 8 + rA;
      const int slot  = sA ^ (row & 7);
      async_load16(B + (size_t)(tn + row) * K + k0 + slot * 8, (char*)Bs + chunk * 1024);
    }
    __syncthreads();
#pragma unroll
    for (int kk = 0; kk < 2; ++kk) {
      bf16x8 af[4], bfv[4];
#pragma unroll
      for (int im = 0; im < 4; ++im) {
        const int R = wr * 64 + im * 16 + (lane & 15);
        const int s = (kk * 4 + (lane >> 4)) ^ (R & 7);
        af[im] = *(const bf16x8*)((const char*)As + R * 128 + s * 16);
      }
#pragma unroll
      for (int in_ = 0; in_ < 4; ++in_) {
        const int R = wc * 64 + in_ * 16 + (lane & 15);
        const int s = (kk * 4 + (lane >> 4)) ^ (R & 7);
        bfv[in_] = *(const bf16x8*)((const char*)Bs + R * 128 + s * 16);
      }
#pragma unroll
      for (int im = 0; im < 4; ++im)
#pragma unroll
        for (int in_ = 0; in_ < 4; ++in_)
          acc[im][in_] = __builtin_amdgcn_mfma_f32_16x16x32_bf16(
              af[im], bfv[in_], acc[im][in_], 0, 0, 0);
    }
    __syncthreads();
  }

  const int cn  = lane & 15;
  const int cr4 = (lane >> 4) * 4;
#pragma unroll
  for (int im = 0; im < 4; ++im) {
#pragma unroll
    for (int in_ = 0; in_ < 4; ++in_) {
      const int col = tn + wc * 64 + in_ * 16 + cn;
      const float bv = bias[col];
#pragma unroll
      for (int j = 0; j < 4; ++j) {
        const int row = tm + wr * 64 + im * 16 + cr4 + j;
        if (row < M) {
          const float v = acc[im][in_][j] + bv;
          if (EPI == 0) {
            ((u16*)Cout)[(size_t)row * ldc + col] = f2bf(gelu_exact(v));
          } else {
            const int b = row / 197, p = row % 197;
            ((float*)Cout)[((size_t)(b * 203 + 6 + p)) * 768 + col] = v;
          }
        }
      }
    }
  }
}

// ---------------- candidate GEMM ----------------
__global__ __launch_bounds__(256, 2) void cand_gemm(
    const u16* __restrict__ hid, const u16* __restrict__ wao,
    const float* __restrict__ bout, const int* __restrict__ rstar,
    const float* __restrict__ wstar, float* __restrict__ out) {
  __shared__ u16 As[64 * 64];
  __shared__ u16 Bs[128 * 64];
  const int g = blockIdx.y, n = g >> 1, r = g & 1;
  const int src_a = (r == 0) ? (n >> 1) : (3 + (n & 1));
  const int dst_a = (r == 1) ? (n >> 1) : (3 + (n & 1));
  const int tn = blockIdx.x * 128;
  const int lane = threadIdx.x & 63, wid = threadIdx.x >> 6;
  const int rA = lane >> 3, sA = lane & 7;
  const u16* Bbase = wao + (size_t)dst_a * 768 * 3072;
  f32x4 acc[4][2] = {};
  for (int ks = 0; ks < 48; ++ks) {
    const int k0 = ks << 6;
#pragma unroll
    for (int c = 0; c < 2; ++c) {
      const int chunk = wid * 2 + c;
      const int row   = chunk * 8 + rA;
      const int slot  = sA ^ (row & 7);
      async_load16(hid + (size_t)(row * 6 + n) * 15360 + src_a * 3072 + k0 + slot * 8,
                   (char*)As + chunk * 1024);
    }
#pragma unroll
    for (int c = 0; c < 4; ++c) {
      const int chunk = wid * 4 + c;
      const int row   = chunk * 8 + rA;
      const int slot  = sA ^ (row & 7);
      async_load16(Bbase + (size_t)(tn + row) * 3072 + k0 + slot * 8,
                   (char*)Bs + chunk * 1024);
    }
    __syncthreads();
#pragma unroll
    for (int kk = 0; kk < 2; ++kk) {
      bf16x8 af[4], bfv[2];
#pragma unroll
      for (int im = 0; im < 4; ++im) {
        const int R = im * 16 + (lane & 15);
        const int s = (kk * 4 + (lane >> 4)) ^ (R & 7);
        af[im] = *(const bf16x8*)((const char*)As + R * 128 + s * 16);
      }
#pragma unroll
      for (int in_ = 0; in_ < 2; ++in_) {
        const int R = wid * 32 + in_ * 16 + (lane & 15);
        const int s = (kk * 4 + (lane >> 4)) ^ (R & 7);
        bfv[in_] = *(const bf16x8*)((const char*)Bs + R * 128 + s * 16);
      }
#pragma unroll
      for (int im = 0; im < 4; ++im)
#pragma unroll
        for (int in_ = 0; in_ < 2; ++in_)
          acc[im][in_] = __builtin_amdgcn_mfma_f32_16x16x32_bf16(
              af[im], bfv[in_], acc[im][in_], 0, 0, 0);
    }
    __syncthreads();
  }
  const int cn = lane & 15, cr4 = (lane >> 4) * 4;
#pragma unroll
  for (int im = 0; im < 4; ++im)
#pragma unroll
    for (int in_ = 0; in_ < 2; ++in_) {
      const int col = tn + wid * 32 + in_ * 16 + cn;
      const float bv = bout[dst_a * 768 + col];
#pragma unroll
      for (int j = 0; j < 4; ++j) {
        const int b = im * 16 + cr4 + j;
        const int idx = b * 6 + n;
        if (rstar[idx] == r)
          out[((size_t)(b * 203 + n)) * 768 + col] = (acc[im][in_][j] + bv) * wstar[idx];
      }
    }
}

// ---------------- launch ----------------
extern "C" void kernel_launch(void* const* d_in, const int* in_sizes, int n_in,
                              void* d_out, int out_size, void* d_ws, size_t ws_size,
                              hipStream_t stream) {
  const float* x     = (const float*)d_in[0];
  const float* fc1w  = (const float*)d_in[1];
  const float* fc1b  = (const float*)d_in[2];
  const float* fc2w  = (const float*)d_in[3];
  const float* fc2b  = (const float*)d_in[4];
  const float* gpair = (const float*)d_in[5];
  const float* aiw   = (const float*)d_in[6];
  const float* aib   = (const float*)d_in[7];
  const float* aow   = (const float*)d_in[8];
  const float* aob   = (const float*)d_in[9];
  const float* bbias = (const float*)d_in[10];
  float* out = (float*)d_out;

  char* ws = (char*)d_ws;
  u16* xp   = (u16*)(ws + 0);          // 12608x768 bf16
  u16* xc   = (u16*)(ws + 19365888);   // 384x768
  u16* w1   = (u16*)(ws + 19955712);   // 3072x768
  u16* w2   = (u16*)(ws + 24674304);   // 768x3072
  u16* wai  = (u16*)(ws + 29392896);   // 5x3072x768
  u16* wao  = (u16*)(ws + 52985856);   // 5x768x3072
  u16* hb   = (u16*)(ws + 76578816);   // 12608x3072
  u16* hid  = (u16*)(ws + 154042368);  // 384x15360
  int*   rstar = (int*)(ws + 165838848);
  float* wstar = (float*)(ws + 165840384);
  if (ws_size < 165841920) return;

  cvt_x<<<9744, 256, 0, stream>>>(x, xc, xp);
  cvt4<<<27648, 256, 0, stream>>>(fc1w, w1, fc2w, w2, aiw, wai, aow, wao);
  gate_kernel<<<96, 256, 0, stream>>>(x, gpair, bbias, rstar, wstar);
  // patch fc1 + gelu -> hb (bf16), 8-phase 256^2
  gemm8<0><<<dim3(12, 50), 512, 0, stream>>>(xp, w1, fc1b, hb, 12608, 768, 3072);
  // hid_all = gelu(cls @ atom_in_w^T + b) for all 5 atoms
  gemm_bt<0><<<dim3(120, 3), 256, 0, stream>>>(xc, wai, aib, hid, 384, 768, 15360);
  // patch fc2 -> d_out (scatter), 8-phase 256^2
  gemm8<1><<<dim3(3, 50), 512, 0, stream>>>(hb, w2, fc2b, out, 12608, 3072, 768);
  // route candidates, chosen one written * prob
  cand_gemm<<<dim3(6, 12), 256, 0, stream>>>(hid, wao, aob, rstar, wstar, out);
}

// Round 3
// 368.288 us; speedup vs baseline: 1.0180x; 1.0180x over previous
//
#include <hip/hip_runtime.h>
#include <hip/hip_bf16.h>

// Mlp_moe: patch MLP + 6-class 2-route MoE on cls tokens.
// Round 3: 128^2 tiles with T3-minimum 2-phase (dbuf LDS, prefetch-next, single barrier/K-tile).

typedef __bf16 bf16x8 __attribute__((ext_vector_type(8)));
typedef float f32x4 __attribute__((ext_vector_type(4)));
typedef unsigned short u16;

#define DEVINL __device__ __forceinline__

DEVINL u16 f2bf(float f) {
  unsigned int u = __builtin_bit_cast(unsigned int, f);
  u += 0x7FFFu + ((u >> 16) & 1u);
  return (u16)(u >> 16);
}

DEVINL float gelu_exact(float v) {
  return 0.5f * v * (1.0f + erff(v * 0.70710678118654752440f));
}

DEVINL void async_load16(const void* g, void* l) {
  __builtin_amdgcn_global_load_lds(
      (const __attribute__((address_space(1))) unsigned int*)g,
      (__attribute__((address_space(3))) unsigned int*)l, 16, 0, 0);
}

#define MFMA_BF16 __builtin_amdgcn_mfma_f32_16x16x32_bf16

// ---------------- fused conversion kernel ----------------
// R0 (9744 blocks):  split x (64,203,768) f32 -> xc (384,768) bf16 + xp (12608,768) bf16
// R1..R4: f32->bf16 for fc1_w (2304), fc2_w (2304), atom_in_w (11520), atom_out_w (11520)
__global__ void cvt_all(const float* __restrict__ x, u16* __restrict__ xc, u16* __restrict__ xp,
                        const float* __restrict__ s1, u16* __restrict__ d1,
                        const float* __restrict__ s2, u16* __restrict__ d2,
                        const float* __restrict__ s3, u16* __restrict__ d3,
                        const float* __restrict__ s4, u16* __restrict__ d4) {
  int b = blockIdx.x;
  if (b < 9744) {
    const int e = (b * 256 + threadIdx.x) * 4;
    const int t = e / 768, d = e % 768;
    const int bb = t / 203, i = t % 203;
    const float4 v = *(const float4*)(x + e);
    ushort4 u;
    u.x = f2bf(v.x); u.y = f2bf(v.y); u.z = f2bf(v.z); u.w = f2bf(v.w);
    if (i < 6) *(ushort4*)(xc + (size_t)(bb * 6 + i) * 768 + d) = u;
    else       *(ushort4*)(xp + (size_t)(bb * 197 + (i - 6)) * 768 + d) = u;
    return;
  }
  b -= 9744;
  const float* s; u16* d;
  if (b < 2304) { s = s1; d = d1; }
  else if (b < 4608) { s = s2; d = d2; b -= 2304; }
  else if (b < 16128) { s = s3; d = d3; b -= 4608; }
  else { s = s4; d = d4; b -= 16128; }
  const int i = (b * 256 + threadIdx.x) * 4;
  const float4 v = *(const float4*)(s + i);
  ushort4 u;
  u.x = f2bf(v.x); u.y = f2bf(v.y); u.z = f2bf(v.z); u.w = f2bf(v.w);
  *(ushort4*)(d + i) = u;
}

// ---------------- gate / routing decision (fp64 accum) ----------------
__global__ void gate_kernel(const float* __restrict__ x,
                            const float* __restrict__ gate_pair,
                            const float* __restrict__ balance_bias,
                            int* __restrict__ rstar, float* __restrict__ wstar) {
  const int lane = threadIdx.x & 63, wid = threadIdx.x >> 6;
  const int idx = blockIdx.x * 4 + wid;
  const int b = idx / 6, n = idx % 6;
  const float* xv = x + (size_t)(b * 203 + n) * 768;
  const float* w0 = gate_pair + (size_t)(n * 2 + 0) * 768;
  const float* w1 = gate_pair + (size_t)(n * 2 + 1) * 768;
  double xx = 0, a00 = 0, a11 = 0, d0 = 0, d1 = 0;
  for (int d = lane; d < 768; d += 64) {
    double xd = xv[d], g0 = w0[d], g1 = w1[d];
    xx += xd * xd; a00 += g0 * g0; a11 += g1 * g1; d0 += xd * g0; d1 += xd * g1;
  }
#pragma unroll
  for (int off = 32; off; off >>= 1) {
    xx  += __shfl_xor(xx, off);
    a00 += __shfl_xor(a00, off);
    a11 += __shfl_xor(a11, off);
    d0  += __shfl_xor(d0, off);
    d1  += __shfl_xor(d1, off);
  }
  if (lane == 0) {
    double nx = fmax(sqrt(xx), 1e-12), n0 = fmax(sqrt(a00), 1e-12), n1 = fmax(sqrt(a11), 1e-12);
    double l0 = d0 / (nx * n0) + (double)balance_bias[n * 2 + 0];
    double l1 = d1 / (nx * n1) + (double)balance_bias[n * 2 + 1];
    const int r = (l1 > l0) ? 1 : 0;
    double m = fmax(l0, l1);
    double e0 = exp(l0 - m), e1 = exp(l1 - m);
    rstar[idx] = r;
    wstar[idx] = (float)(((r == 1) ? e1 : e0) / (e0 + e1));
  }
}

// ---------------- 128x128 2-phase dbuf GEMM: C = A(MxK) * B(NxK)^T + bias ----------------
// LDS [2][128 rows][8 slots x 16B]; slot swizzle s^(row&7). stage(t+1) issued BEFORE
// compute(t); single __syncthreads per K-tile (its vmcnt(0) drain lands post-compute).
template <int EPI>
__global__ __launch_bounds__(256, 2) void gemm_bt(
    const u16* __restrict__ A, const u16* __restrict__ B,
    const float* __restrict__ bias, void* __restrict__ Cout,
    int M, int K, int ldc) {
  __shared__ u16 As[2][128 * 64];
  __shared__ u16 Bs[2][128 * 64];
  const int tid = threadIdx.x;
  const int lane = tid & 63, wid = tid >> 6;
  const int wr = wid >> 1, wc = wid & 1;
  const int tm = blockIdx.y * 128, tn = blockIdx.x * 128;
  const int ksteps = K >> 6;

  f32x4 acc[4][4] = {};

  auto stage = [&](int buf, int t) {
    const int k0 = t << 6;
#pragma unroll
    for (int j = 0; j < 4; ++j) {
      const int row = j * 32 + (tid >> 3);                 // 0..127
      const int sl  = (tid & 7) ^ (row & 7);               // inverse-swizzled source slot
      int ga = tm + row;
      ga = ga < M ? ga : (M - 1);                          // clamp tail rows (never stored)
      async_load16(A + (size_t)ga * K + k0 + sl * 8,
                   (char*)As[buf] + (j * 32 + wid * 8) * 128);
      async_load16(B + (size_t)(tn + row) * K + k0 + sl * 8,
                   (char*)Bs[buf] + (j * 32 + wid * 8) * 128);
    }
  };
  auto compute = [&](int buf) {
    const u16* as = As[buf];
    const u16* bs = Bs[buf];
#pragma unroll
    for (int kk = 0; kk < 2; ++kk) {
      bf16x8 af[4], bfv[4];
#pragma unroll
      for (int im = 0; im < 4; ++im) {
        const int R = wr * 64 + im * 16 + (lane & 15);
        const int s = (kk * 4 + (lane >> 4)) ^ (R & 7);
        af[im] = *(const bf16x8*)(as + R * 64 + s * 8);
      }
#pragma unroll
      for (int in_ = 0; in_ < 4; ++in_) {
        const int R = wc * 64 + in_ * 16 + (lane & 15);
        const int s = (kk * 4 + (lane >> 4)) ^ (R & 7);
        bfv[in_] = *(const bf16x8*)(bs + R * 64 + s * 8);
      }
#pragma unroll
      for (int im = 0; im < 4; ++im)
#pragma unroll
        for (int in_ = 0; in_ < 4; ++in_)
          acc[im][in_] = MFMA_BF16(af[im], bfv[in_], acc[im][in_], 0, 0, 0);
    }
  };

  stage(0, 0);
  __syncthreads();
  for (int t = 0; t < ksteps; ++t) {
    if (t + 1 < ksteps) stage((t + 1) & 1, t + 1);
    compute(t & 1);
    __syncthreads();
  }

  const int cn = lane & 15, cr4 = (lane >> 4) * 4;
#pragma unroll
  for (int im = 0; im < 4; ++im) {
#pragma unroll
    for (int in_ = 0; in_ < 4; ++in_) {
      const int col = tn + wc * 64 + in_ * 16 + cn;
      const float bv = bias[col];
#pragma unroll
      for (int j = 0; j < 4; ++j) {
        const int row = tm + wr * 64 + im * 16 + cr4 + j;
        if (row < M) {
          const float v = acc[im][in_][j] + bv;
          if (EPI == 0) {
            ((u16*)Cout)[(size_t)row * ldc + col] = f2bf(gelu_exact(v));
          } else {
            const int b = row / 197, p = row % 197;
            ((float*)Cout)[((size_t)(b * 203 + 6 + p)) * 768 + col] = v;
          }
        }
      }
    }
  }
}

// ---------------- candidate GEMM: per (n,r,row-half) 32x128 tile, dbuf 2-phase ----------------
// grid (6, 12, 2): x = col tile (BN=128), y = (n,r), z = batch half (BM=32).
__global__ __launch_bounds__(256, 4) void cand_gemm(
    const u16* __restrict__ hid, const u16* __restrict__ wao,
    const float* __restrict__ bout, const int* __restrict__ rstar,
    const float* __restrict__ wstar, float* __restrict__ out) {
  __shared__ u16 As[2][32 * 64];
  __shared__ u16 Bs[2][128 * 64];
  const int g = blockIdx.y, n = g >> 1, r = g & 1;
  const int src_a = (r == 0) ? (n >> 1) : (3 + (n & 1));   // src[n] = {n/2, 3+(n&1)}
  const int dst_a = (r == 1) ? (n >> 1) : (3 + (n & 1));   // dst[n][r] = src[n][1-r]
  const int tn = blockIdx.x * 128;
  const int b0 = blockIdx.z * 32;
  const int tid = threadIdx.x, lane = tid & 63, wid = tid >> 6;
  const u16* Bbase = wao + (size_t)dst_a * 768 * 3072;
  const u16* Abase = hid + (size_t)src_a * 3072 + (size_t)n * 15360;

  f32x4 acc[2][2] = {};

  auto stage = [&](int buf, int t) {
    const int k0 = t << 6;
    {  // A: 32 rows (batches), 1 load/thread
      const int row = tid >> 3;                 // 0..31
      const int sl  = (tid & 7) ^ (row & 7);
      async_load16(Abase + (size_t)(b0 + row) * 6 * 15360 + k0 + sl * 8,
                   (char*)As[buf] + wid * 8 * 128);
    }
#pragma unroll
    for (int j = 0; j < 4; ++j) {  // B: 128 rows
      const int row = j * 32 + (tid >> 3);
      const int sl  = (tid & 7) ^ (row & 7);
      async_load16(Bbase + (size_t)(tn + row) * 3072 + k0 + sl * 8,
                   (char*)Bs[buf] + (j * 32 + wid * 8) * 128);
    }
  };
  auto compute = [&](int buf) {
    const u16* as = As[buf];
    const u16* bs = Bs[buf];
#pragma unroll
    for (int kk = 0; kk < 2; ++kk) {
      bf16x8 af[2], bfv[2];
#pragma unroll
      for (int im = 0; im < 2; ++im) {
        const int R = im * 16 + (lane & 15);
        const int s = (kk * 4 + (lane >> 4)) ^ (R & 7);
        af[im] = *(const bf16x8*)(as + R * 64 + s * 8);
      }
#pragma unroll
      for (int q = 0; q < 2; ++q) {
        const int R = wid * 32 + q * 16 + (lane & 15);
        const int s = (kk * 4 + (lane >> 4)) ^ (R & 7);
        bfv[q] = *(const bf16x8*)(bs + R * 64 + s * 8);
      }
#pragma unroll
      for (int im = 0; im < 2; ++im)
#pragma unroll
        for (int q = 0; q < 2; ++q)
          acc[im][q] = MFMA_BF16(af[im], bfv[q], acc[im][q], 0, 0, 0);
    }
  };

  stage(0, 0);
  __syncthreads();
  for (int t = 0; t < 48; ++t) {
    if (t + 1 < 48) stage((t + 1) & 1, t + 1);
    compute(t & 1);
    __syncthreads();
  }

  const int cn = lane & 15, cr4 = (lane >> 4) * 4;
#pragma unroll
  for (int im = 0; im < 2; ++im)
#pragma unroll
    for (int q = 0; q < 2; ++q) {
      const int col = tn + wid * 32 + q * 16 + cn;
      const float bv = bout[dst_a * 768 + col];
#pragma unroll
      for (int j = 0; j < 4; ++j) {
        const int b = b0 + im * 16 + cr4 + j;
        const int idx = b * 6 + n;
        if (rstar[idx] == r)
          out[((size_t)(b * 203 + n)) * 768 + col] = (acc[im][q][j] + bv) * wstar[idx];
      }
    }
}

// ---------------- launch ----------------
extern "C" void kernel_launch(void* const* d_in, const int* in_sizes, int n_in,
                              void* d_out, int out_size, void* d_ws, size_t ws_size,
                              hipStream_t stream) {
  const float* x     = (const float*)d_in[0];
  const float* fc1w  = (const float*)d_in[1];
  const float* fc1b  = (const float*)d_in[2];
  const float* fc2w  = (const float*)d_in[3];
  const float* fc2b  = (const float*)d_in[4];
  const float* gpair = (const float*)d_in[5];
  const float* aiw   = (const float*)d_in[6];
  const float* aib   = (const float*)d_in[7];
  const float* aow   = (const float*)d_in[8];
  const float* aob   = (const float*)d_in[9];
  const float* bbias = (const float*)d_in[10];
  float* out = (float*)d_out;

  char* ws = (char*)d_ws;
  u16* xp   = (u16*)(ws + 0);          // 12608x768 bf16
  u16* xc   = (u16*)(ws + 19365888);   // 384x768
  u16* w1   = (u16*)(ws + 19955712);   // 3072x768
  u16* w2   = (u16*)(ws + 24674304);   // 768x3072
  u16* wai  = (u16*)(ws + 29392896);   // 5x3072x768
  u16* wao  = (u16*)(ws + 52985856);   // 5x768x3072
  u16* hb   = (u16*)(ws + 76578816);   // 12608x3072
  u16* hid  = (u16*)(ws + 154042368);  // 384x15360
  int*   rstar = (int*)(ws + 165838848);
  float* wstar = (float*)(ws + 165840384);
  if (ws_size < 165841920) return;

  cvt_all<<<37392, 256, 0, stream>>>(x, xc, xp, fc1w, w1, fc2w, w2, aiw, wai, aow, wao);
  gate_kernel<<<96, 256, 0, stream>>>(x, gpair, bbias, rstar, wstar);
  // patch fc1 + gelu -> hb (bf16)
  gemm_bt<0><<<dim3(24, 99), 256, 0, stream>>>(xp, w1, fc1b, hb, 12608, 768, 3072);
  // hid_all = gelu(cls @ atom_in_w^T + b) for all 5 atoms
  gemm_bt<0><<<dim3(120, 3), 256, 0, stream>>>(xc, wai, aib, hid, 384, 768, 15360);
  // patch fc2 -> d_out (scatter to b*203+6+p rows)
  gemm_bt<1><<<dim3(6, 99), 256, 0, stream>>>(hb, w2, fc2b, out, 12608, 3072, 768);
  // route candidates, chosen one written * prob
  cand_gemm<<<dim3(6, 12, 2), 256, 0, stream>>>(hid, wao, aob, rstar, wstar, out);
}

// Round 4
// 359.252 us; speedup vs baseline: 1.0436x; 1.0252x over previous
//
#include <hip/hip_runtime.h>
#include <hip/hip_bf16.h>

// Mlp_moe: patch MLP + 6-class 2-route MoE on cls tokens.
// Round 4: back to round-1's proven 2-barrier schedule; 32x32x16 MFMA + bigger tiles
// to halve per-FLOP instruction overhead (round-1 was VALU-issue-bound: 47% VALU vs 25% MFMA).

typedef __bf16 bf16x8 __attribute__((ext_vector_type(8)));
typedef float f32x4 __attribute__((ext_vector_type(4)));
typedef float f32x16 __attribute__((ext_vector_type(16)));
typedef unsigned short u16;

#define DEVINL __device__ __forceinline__

DEVINL u16 f2bf(float f) {
  unsigned int u = __builtin_bit_cast(unsigned int, f);
  u += 0x7FFFu + ((u >> 16) & 1u);
  return (u16)(u >> 16);
}

DEVINL float gelu_exact(float v) {
  return 0.5f * v * (1.0f + erff(v * 0.70710678118654752440f));
}

DEVINL void async_load16(const void* g, void* l) {
  __builtin_amdgcn_global_load_lds(
      (const __attribute__((address_space(1))) unsigned int*)g,
      (__attribute__((address_space(3))) unsigned int*)l, 16, 0, 0);
}

#define MFMA32 __builtin_amdgcn_mfma_f32_32x32x16_bf16
#define MFMA16 __builtin_amdgcn_mfma_f32_16x16x32_bf16

// ---------------- fused conversion kernel ----------------
__global__ void cvt_all(const float* __restrict__ x, u16* __restrict__ xc, u16* __restrict__ xp,
                        const float* __restrict__ s1, u16* __restrict__ d1,
                        const float* __restrict__ s2, u16* __restrict__ d2,
                        const float* __restrict__ s3, u16* __restrict__ d3,
                        const float* __restrict__ s4, u16* __restrict__ d4) {
  int b = blockIdx.x;
  if (b < 9744) {
    const int e = (b * 256 + threadIdx.x) * 4;
    const int t = e / 768, d = e % 768;
    const int bb = t / 203, i = t % 203;
    const float4 v = *(const float4*)(x + e);
    ushort4 u;
    u.x = f2bf(v.x); u.y = f2bf(v.y); u.z = f2bf(v.z); u.w = f2bf(v.w);
    if (i < 6) *(ushort4*)(xc + (size_t)(bb * 6 + i) * 768 + d) = u;
    else       *(ushort4*)(xp + (size_t)(bb * 197 + (i - 6)) * 768 + d) = u;
    return;
  }
  b -= 9744;
  const float* s; u16* d;
  if (b < 2304) { s = s1; d = d1; }
  else if (b < 4608) { s = s2; d = d2; b -= 2304; }
  else if (b < 16128) { s = s3; d = d3; b -= 4608; }
  else { s = s4; d = d4; b -= 16128; }
  const int i = (b * 256 + threadIdx.x) * 4;
  const float4 v = *(const float4*)(s + i);
  ushort4 u;
  u.x = f2bf(v.x); u.y = f2bf(v.y); u.z = f2bf(v.z); u.w = f2bf(v.w);
  *(ushort4*)(d + i) = u;
}

// ---------------- gate / routing decision (fp64 accum) ----------------
__global__ void gate_kernel(const float* __restrict__ x,
                            const float* __restrict__ gate_pair,
                            const float* __restrict__ balance_bias,
                            int* __restrict__ rstar, float* __restrict__ wstar) {
  const int lane = threadIdx.x & 63, wid = threadIdx.x >> 6;
  const int idx = blockIdx.x * 4 + wid;
  const int b = idx / 6, n = idx % 6;
  const float* xv = x + (size_t)(b * 203 + n) * 768;
  const float* w0 = gate_pair + (size_t)(n * 2 + 0) * 768;
  const float* w1 = gate_pair + (size_t)(n * 2 + 1) * 768;
  double xx = 0, a00 = 0, a11 = 0, d0 = 0, d1 = 0;
  for (int d = lane; d < 768; d += 64) {
    double xd = xv[d], g0 = w0[d], g1 = w1[d];
    xx += xd * xd; a00 += g0 * g0; a11 += g1 * g1; d0 += xd * g0; d1 += xd * g1;
  }
#pragma unroll
  for (int off = 32; off; off >>= 1) {
    xx  += __shfl_xor(xx, off);
    a00 += __shfl_xor(a00, off);
    a11 += __shfl_xor(a11, off);
    d0  += __shfl_xor(d0, off);
    d1  += __shfl_xor(d1, off);
  }
  if (lane == 0) {
    double nx = fmax(sqrt(xx), 1e-12), n0 = fmax(sqrt(a00), 1e-12), n1 = fmax(sqrt(a11), 1e-12);
    double l0 = d0 / (nx * n0) + (double)balance_bias[n * 2 + 0];
    double l1 = d1 / (nx * n1) + (double)balance_bias[n * 2 + 1];
    const int r = (l1 > l0) ? 1 : 0;
    double m = fmax(l0, l1);
    double e0 = exp(l0 - m), e1 = exp(l1 - m);
    rstar[idx] = r;
    wstar[idx] = (float)(((r == 1) ? e1 : e0) / (e0 + e1));
  }
}

// ---------------- 32x32x16-MFMA GEMM: C = A(MxK)*B(NxK)^T + bias ----------------
// Block tile (WM*64) x 128, 4 waves (2 row x 2 col), wave tile (WM*32) x 64 = WM x 2 of 32x32.
// BK=64, single-buffer LDS, 2-barrier schedule (m97 lineage: implicit multi-block overlap).
// A/B frag: lane l -> row l&31, k-half l>>5 (8 contiguous k). Slot swizzle ^(row&7) both sides.
// C/D: col = lane&31, row = (r&3) + 8*(r>>2) + 4*(lane>>5)  [m74/m101 verified].
template <int WM, int EPI>
__global__ __launch_bounds__(256, 2) void gemm32(
    const u16* __restrict__ A, const u16* __restrict__ B,
    const float* __restrict__ bias, void* __restrict__ Cout,
    int M, int K, int ldc) {
  __shared__ u16 As[WM * 64 * 64];
  __shared__ u16 Bs[128 * 64];
  const int tid = threadIdx.x;
  const int lane = tid & 63, wid = tid >> 6;
  const int wr = wid >> 1, wc = wid & 1;
  const int tm = blockIdx.y * (WM * 64), tn = blockIdx.x * 128;
  const int ksteps = K >> 6;

  f32x16 acc[WM][2] = {};

  for (int t = 0; t < ksteps; ++t) {
    const int k0 = t << 6;
    // stage A (WM*64 rows) + B (128 rows), 16B/load, inverse-swizzled source slot
#pragma unroll
    for (int j = 0; j < WM * 2; ++j) {
      const int row = j * 32 + (tid >> 3);
      const int sl  = (tid & 7) ^ (row & 7);
      int ga = tm + row;
      ga = ga < M ? ga : (M - 1);  // clamp tail rows (never stored)
      async_load16(A + (size_t)ga * K + k0 + sl * 8, (char*)As + j * 4096 + tid * 16);
    }
#pragma unroll
    for (int j = 0; j < 4; ++j) {
      const int row = j * 32 + (tid >> 3);
      const int sl  = (tid & 7) ^ (row & 7);
      async_load16(B + (size_t)(tn + row) * K + k0 + sl * 8, (char*)Bs + j * 4096 + tid * 16);
    }
    __syncthreads();  // vmcnt(0) drain: staged data visible
#pragma unroll
    for (int ks = 0; ks < 4; ++ks) {
      bf16x8 af[WM], bfv[2];
#pragma unroll
      for (int i = 0; i < WM; ++i) {
        const int R = wr * (WM * 32) + i * 32 + (lane & 31);
        const int g = (ks * 2 + (lane >> 5)) ^ (R & 7);
        af[i] = *(const bf16x8*)((const char*)As + R * 128 + g * 16);
      }
#pragma unroll
      for (int jb = 0; jb < 2; ++jb) {
        const int Cc = wc * 64 + jb * 32 + (lane & 31);
        const int g  = (ks * 2 + (lane >> 5)) ^ (Cc & 7);
        bfv[jb] = *(const bf16x8*)((const char*)Bs + Cc * 128 + g * 16);
      }
#pragma unroll
      for (int i = 0; i < WM; ++i)
#pragma unroll
        for (int jb = 0; jb < 2; ++jb)
          acc[i][jb] = MFMA32(af[i], bfv[jb], acc[i][jb], 0, 0, 0);
    }
    __syncthreads();  // protect single buffer from next stage
  }

  const int rbase = 4 * (lane >> 5);
#pragma unroll
  for (int i = 0; i < WM; ++i)
#pragma unroll
    for (int jb = 0; jb < 2; ++jb) {
      const int col = tn + wc * 64 + jb * 32 + (lane & 31);
      const float bv = bias[col];
#pragma unroll
      for (int r = 0; r < 16; ++r) {
        const int row = tm + wr * (WM * 32) + i * 32 + (r & 3) + 8 * (r >> 2) + rbase;
        if (row < M) {
          const float v = acc[i][jb][r] + bv;
          if (EPI == 0) {
            ((u16*)Cout)[(size_t)row * ldc + col] = f2bf(gelu_exact(v));
          } else {
            const int b = row / 197, pp = row % 197;
            ((float*)Cout)[((size_t)(b * 203 + 6 + pp)) * 768 + col] = v;
          }
        }
      }
    }
}

// ---------------- candidate GEMM: per (n,r,row-half) 32x128 tile (16x16 MFMA) ----------------
__global__ __launch_bounds__(256, 4) void cand_gemm(
    const u16* __restrict__ hid, const u16* __restrict__ wao,
    const float* __restrict__ bout, const int* __restrict__ rstar,
    const float* __restrict__ wstar, float* __restrict__ out) {
  __shared__ u16 As[2][32 * 64];
  __shared__ u16 Bs[2][128 * 64];
  const int g = blockIdx.y, n = g >> 1, r = g & 1;
  const int src_a = (r == 0) ? (n >> 1) : (3 + (n & 1));
  const int dst_a = (r == 1) ? (n >> 1) : (3 + (n & 1));
  const int tn = blockIdx.x * 128;
  const int b0 = blockIdx.z * 32;
  const int tid = threadIdx.x, lane = tid & 63, wid = tid >> 6;
  const u16* Bbase = wao + (size_t)dst_a * 768 * 3072;
  const u16* Abase = hid + (size_t)src_a * 3072 + (size_t)n * 15360;

  f32x4 acc[2][2] = {};

  auto stage = [&](int buf, int t) {
    const int k0 = t << 6;
    {
      const int row = tid >> 3;
      const int sl  = (tid & 7) ^ (row & 7);
      async_load16(Abase + (size_t)(b0 + row) * 6 * 15360 + k0 + sl * 8,
                   (char*)As[buf] + wid * 8 * 128);
    }
#pragma unroll
    for (int j = 0; j < 4; ++j) {
      const int row = j * 32 + (tid >> 3);
      const int sl  = (tid & 7) ^ (row & 7);
      async_load16(Bbase + (size_t)(tn + row) * 3072 + k0 + sl * 8,
                   (char*)Bs[buf] + (j * 32 + wid * 8) * 128);
    }
  };
  auto compute = [&](int buf) {
    const u16* as = As[buf];
    const u16* bs = Bs[buf];
#pragma unroll
    for (int kk = 0; kk < 2; ++kk) {
      bf16x8 af[2], bfv[2];
#pragma unroll
      for (int im = 0; im < 2; ++im) {
        const int R = im * 16 + (lane & 15);
        const int s = (kk * 4 + (lane >> 4)) ^ (R & 7);
        af[im] = *(const bf16x8*)(as + R * 64 + s * 8);
      }
#pragma unroll
      for (int q = 0; q < 2; ++q) {
        const int R = wid * 32 + q * 16 + (lane & 15);
        const int s = (kk * 4 + (lane >> 4)) ^ (R & 7);
        bfv[q] = *(const bf16x8*)(bs + R * 64 + s * 8);
      }
#pragma unroll
      for (int im = 0; im < 2; ++im)
#pragma unroll
        for (int q = 0; q < 2; ++q)
          acc[im][q] = MFMA16(af[im], bfv[q], acc[im][q], 0, 0, 0);
    }
  };

  stage(0, 0);
  __syncthreads();
  for (int t = 0; t < 48; ++t) {
    if (t + 1 < 48) stage((t + 1) & 1, t + 1);
    compute(t & 1);
    __syncthreads();
  }

  const int cn = lane & 15, cr4 = (lane >> 4) * 4;
#pragma unroll
  for (int im = 0; im < 2; ++im)
#pragma unroll
    for (int q = 0; q < 2; ++q) {
      const int col = tn + wid * 32 + q * 16 + cn;
      const float bv = bout[dst_a * 768 + col];
#pragma unroll
      for (int j = 0; j < 4; ++j) {
        const int b = b0 + im * 16 + cr4 + j;
        const int idx = b * 6 + n;
        if (rstar[idx] == r)
          out[((size_t)(b * 203 + n)) * 768 + col] = (acc[im][q][j] + bv) * wstar[idx];
      }
    }
}

// ---------------- launch ----------------
extern "C" void kernel_launch(void* const* d_in, const int* in_sizes, int n_in,
                              void* d_out, int out_size, void* d_ws, size_t ws_size,
                              hipStream_t stream) {
  const float* x     = (const float*)d_in[0];
  const float* fc1w  = (const float*)d_in[1];
  const float* fc1b  = (const float*)d_in[2];
  const float* fc2w  = (const float*)d_in[3];
  const float* fc2b  = (const float*)d_in[4];
  const float* gpair = (const float*)d_in[5];
  const float* aiw   = (const float*)d_in[6];
  const float* aib   = (const float*)d_in[7];
  const float* aow   = (const float*)d_in[8];
  const float* aob   = (const float*)d_in[9];
  const float* bbias = (const float*)d_in[10];
  float* out = (float*)d_out;

  char* ws = (char*)d_ws;
  u16* xp   = (u16*)(ws + 0);          // 12608x768 bf16
  u16* xc   = (u16*)(ws + 19365888);   // 384x768
  u16* w1   = (u16*)(ws + 19955712);   // 3072x768
  u16* w2   = (u16*)(ws + 24674304);   // 768x3072
  u16* wai  = (u16*)(ws + 29392896);   // 5x3072x768
  u16* wao  = (u16*)(ws + 52985856);   // 5x768x3072
  u16* hb   = (u16*)(ws + 76578816);   // 12608x3072
  u16* hid  = (u16*)(ws + 154042368);  // 384x15360
  int*   rstar = (int*)(ws + 165838848);
  float* wstar = (float*)(ws + 165840384);
  if (ws_size < 165841920) return;

  cvt_all<<<37392, 256, 0, stream>>>(x, xc, xp, fc1w, w1, fc2w, w2, aiw, wai, aow, wao);
  gate_kernel<<<96, 256, 0, stream>>>(x, gpair, bbias, rstar, wstar);
  // patch fc1 + gelu -> hb (bf16): 256x128 tiles
  gemm32<4, 0><<<dim3(24, 50), 256, 0, stream>>>(xp, w1, fc1b, hb, 12608, 768, 3072);
  // hid_all = gelu(cls @ atom_in_w^T + b): 128x128 tiles
  gemm32<2, 0><<<dim3(120, 3), 256, 0, stream>>>(xc, wai, aib, hid, 384, 768, 15360);
  // patch fc2 -> d_out (scatter): 128x128 tiles
  gemm32<2, 1><<<dim3(6, 99), 256, 0, stream>>>(hb, w2, fc2b, out, 12608, 3072, 768);
  // route candidates, chosen one written * prob
  cand_gemm<<<dim3(6, 12, 2), 256, 0, stream>>>(hid, wao, aob, rstar, wstar, out);
}

// Round 6
// 318.788 us; speedup vs baseline: 1.1761x; 1.1269x over previous
//
#include <hip/hip_runtime.h>
#include <hip/hip_bf16.h>

// Mlp_moe: patch MLP + 6-class 2-route MoE on cls tokens.
// Round 6: round-5 structure (256x128 8-wave, 2-barrier, single-buffer) with the gemm4w
// staging bug fixed (j<4, row=j*32+(tid>>3) -- 256-thread block only covers 32 rows/iter).

typedef __bf16 bf16x8 __attribute__((ext_vector_type(8)));
typedef float f32x4 __attribute__((ext_vector_type(4)));
typedef unsigned short u16;

#define DEVINL __device__ __forceinline__

DEVINL u16 f2bf(float f) {
  unsigned int u = __builtin_bit_cast(unsigned int, f);
  u += 0x7FFFu + ((u >> 16) & 1u);
  return (u16)(u >> 16);
}

// Winitzki erf: abs err ~2e-4 (vs bf16 rounding 0.008), branch-free.
DEVINL float gelu_fast(float v) {
  const float x2 = 0.5f * v * v;  // (v/sqrt2)^2
  const float t = x2 * (1.27323954f + 0.147f * x2) / (1.0f + 0.147f * x2);
  const float r = sqrtf(fmaxf(1.0f - __expf(-t), 0.0f));
  const float e = copysignf(r, v);
  return 0.5f * v * (1.0f + e);
}

DEVINL void async_load16(const void* g, void* l) {
  __builtin_amdgcn_global_load_lds(
      (const __attribute__((address_space(1))) unsigned int*)g,
      (__attribute__((address_space(3))) unsigned int*)l, 16, 0, 0);
}

#define MFMA16 __builtin_amdgcn_mfma_f32_16x16x32_bf16

// ---------------- conversions ----------------
__global__ void cvt_x2(const float* __restrict__ x, u16* __restrict__ xc, u16* __restrict__ xp) {
  const int i = blockIdx.x, b = blockIdx.y;
  const int d = threadIdx.x * 4;
  const float4 v = *(const float4*)(x + ((size_t)(b * 203 + i)) * 768 + d);
  ushort4 u;
  u.x = f2bf(v.x); u.y = f2bf(v.y); u.z = f2bf(v.z); u.w = f2bf(v.w);
  if (i < 6) *(ushort4*)(xc + (size_t)(b * 6 + i) * 768 + d) = u;
  else       *(ushort4*)(xp + (size_t)(b * 197 + (i - 6)) * 768 + d) = u;
}

__global__ void cvt_w(const float* __restrict__ s1, u16* __restrict__ d1,
                      const float* __restrict__ s2, u16* __restrict__ d2,
                      const float* __restrict__ s3, u16* __restrict__ d3,
                      const float* __restrict__ s4, u16* __restrict__ d4) {
  int b = blockIdx.x;
  const float* s; u16* d;
  if (b < 2304) { s = s1; d = d1; }
  else if (b < 4608) { s = s2; d = d2; b -= 2304; }
  else if (b < 16128) { s = s3; d = d3; b -= 4608; }
  else { s = s4; d = d4; b -= 16128; }
  const int i = (b * 256 + threadIdx.x) * 4;
  const float4 v = *(const float4*)(s + i);
  ushort4 u;
  u.x = f2bf(v.x); u.y = f2bf(v.y); u.z = f2bf(v.z); u.w = f2bf(v.w);
  *(ushort4*)(d + i) = u;
}

// ---------------- gate / routing decision (fp64 accum) ----------------
__global__ void gate_kernel(const float* __restrict__ x,
                            const float* __restrict__ gate_pair,
                            const float* __restrict__ balance_bias,
                            int* __restrict__ rstar, float* __restrict__ wstar) {
  const int lane = threadIdx.x & 63, wid = threadIdx.x >> 6;
  const int idx = blockIdx.x * 4 + wid;
  const int b = idx / 6, n = idx % 6;
  const float* xv = x + (size_t)(b * 203 + n) * 768;
  const float* w0 = gate_pair + (size_t)(n * 2 + 0) * 768;
  const float* w1 = gate_pair + (size_t)(n * 2 + 1) * 768;
  double xx = 0, a00 = 0, a11 = 0, d0 = 0, d1 = 0;
  for (int d = lane; d < 768; d += 64) {
    double xd = xv[d], g0 = w0[d], g1 = w1[d];
    xx += xd * xd; a00 += g0 * g0; a11 += g1 * g1; d0 += xd * g0; d1 += xd * g1;
  }
#pragma unroll
  for (int off = 32; off; off >>= 1) {
    xx  += __shfl_xor(xx, off);
    a00 += __shfl_xor(a00, off);
    a11 += __shfl_xor(a11, off);
    d0  += __shfl_xor(d0, off);
    d1  += __shfl_xor(d1, off);
  }
  if (lane == 0) {
    double nx = fmax(sqrt(xx), 1e-12), n0 = fmax(sqrt(a00), 1e-12), n1 = fmax(sqrt(a11), 1e-12);
    double l0 = d0 / (nx * n0) + (double)balance_bias[n * 2 + 0];
    double l1 = d1 / (nx * n1) + (double)balance_bias[n * 2 + 1];
    const int r = (l1 > l0) ? 1 : 0;
    double m = fmax(l0, l1);
    double e0 = exp(l0 - m), e1 = exp(l1 - m);
    rstar[idx] = r;
    wstar[idx] = (float)(((r == 1) ? e1 : e0) / (e0 + e1));
  }
}

// ---------------- 256x128 8-wave GEMM: C = A(MxK)*B(NxK)^T + bias ----------------
// 512 thr = 8 waves (4 M x 2 N), wave tile 64x64 (per-wave code identical to round 1).
// Single-buffer LDS 48KB, 2-barrier K-loop, slot swizzle ^(row&7) both sides.
template <int EPI>
__global__ __launch_bounds__(512, 2) void gemm8w(
    const u16* __restrict__ A, const u16* __restrict__ B,
    const float* __restrict__ bias, void* __restrict__ Cout,
    int M, int K, int ldc) {
  __shared__ u16 As[256 * 64];
  __shared__ u16 Bs[128 * 64];
  const int tid = threadIdx.x;
  const int lane = tid & 63, wid = tid >> 6;
  const int wr = wid >> 1, wc = wid & 1;
  const int tm = blockIdx.y * 256, tn = blockIdx.x * 128;
  const int ksteps = K >> 6;

  f32x4 acc[4][4] = {};

  for (int t = 0; t < ksteps; ++t) {
    const int k0 = t << 6;
    // A: 256 rows, 4 loads/thread (512 thr: tid>>3 spans 0..63)
#pragma unroll
    for (int j = 0; j < 4; ++j) {
      const int row = j * 64 + (tid >> 3);
      const int sl  = (tid & 7) ^ (row & 7);
      int ga = tm + row;
      ga = ga < M ? ga : (M - 1);  // clamp tail rows (never stored)
      async_load16(A + (size_t)ga * K + k0 + sl * 8, (char*)As + row * 128 + (tid & 7) * 16);
    }
    // B: 128 rows, 2 loads/thread
#pragma unroll
    for (int j = 0; j < 2; ++j) {
      const int row = j * 64 + (tid >> 3);
      const int sl  = (tid & 7) ^ (row & 7);
      async_load16(B + (size_t)(tn + row) * K + k0 + sl * 8, (char*)Bs + row * 128 + (tid & 7) * 16);
    }
    __syncthreads();  // vmcnt(0) drain: staged data visible
#pragma unroll
    for (int kk = 0; kk < 2; ++kk) {
      bf16x8 af[4], bfv[4];
#pragma unroll
      for (int im = 0; im < 4; ++im) {
        const int R = wr * 64 + im * 16 + (lane & 15);
        const int s = (kk * 4 + (lane >> 4)) ^ (R & 7);
        af[im] = *(const bf16x8*)((const char*)As + R * 128 + s * 16);
      }
#pragma unroll
      for (int in_ = 0; in_ < 4; ++in_) {
        const int R = wc * 64 + in_ * 16 + (lane & 15);
        const int s = (kk * 4 + (lane >> 4)) ^ (R & 7);
        bfv[in_] = *(const bf16x8*)((const char*)Bs + R * 128 + s * 16);
      }
#pragma unroll
      for (int im = 0; im < 4; ++im)
#pragma unroll
        for (int in_ = 0; in_ < 4; ++in_)
          acc[im][in_] = MFMA16(af[im], bfv[in_], acc[im][in_], 0, 0, 0);
    }
    __syncthreads();  // protect single buffer
  }

  const int cn = lane & 15, cr4 = (lane >> 4) * 4;
#pragma unroll
  for (int im = 0; im < 4; ++im) {
#pragma unroll
    for (int in_ = 0; in_ < 4; ++in_) {
      const int col = tn + wc * 64 + in_ * 16 + cn;
      const float bv = bias[col];
#pragma unroll
      for (int j = 0; j < 4; ++j) {
        const int row = tm + wr * 64 + im * 16 + cr4 + j;
        if (row < M) {
          const float v = acc[im][in_][j] + bv;
          if (EPI == 0) {
            ((u16*)Cout)[(size_t)row * ldc + col] = f2bf(gelu_fast(v));
          } else {
            const int b = row / 197, pp = row % 197;
            ((float*)Cout)[((size_t)(b * 203 + 6 + pp)) * 768 + col] = v;
          }
        }
      }
    }
  }
}

// ---------------- 128x128 4-wave GEMM (hid_all; round-1 structure) ----------------
__global__ __launch_bounds__(256, 2) void gemm4w(
    const u16* __restrict__ A, const u16* __restrict__ B,
    const float* __restrict__ bias, u16* __restrict__ Cout,
    int M, int K, int ldc) {
  __shared__ u16 As[128 * 64];
  __shared__ u16 Bs[128 * 64];
  const int tid = threadIdx.x;
  const int lane = tid & 63, wid = tid >> 6;
  const int wr = wid >> 1, wc = wid & 1;
  const int tm = blockIdx.y * 128, tn = blockIdx.x * 128;
  const int ksteps = K >> 6;

  f32x4 acc[4][4] = {};

  for (int t = 0; t < ksteps; ++t) {
    const int k0 = t << 6;
    // FIX: 256 thr -> tid>>3 spans 0..31; need j<4 with 32-row steps to cover 128 rows.
#pragma unroll
    for (int j = 0; j < 4; ++j) {
      const int row = j * 32 + (tid >> 3);
      const int sl  = (tid & 7) ^ (row & 7);
      int ga = tm + row;
      ga = ga < M ? ga : (M - 1);
      async_load16(A + (size_t)ga * K + k0 + sl * 8, (char*)As + row * 128 + (tid & 7) * 16);
      async_load16(B + (size_t)(tn + row) * K + k0 + sl * 8, (char*)Bs + row * 128 + (tid & 7) * 16);
    }
    __syncthreads();
#pragma unroll
    for (int kk = 0; kk < 2; ++kk) {
      bf16x8 af[4], bfv[4];
#pragma unroll
      for (int im = 0; im < 4; ++im) {
        const int R = wr * 64 + im * 16 + (lane & 15);
        const int s = (kk * 4 + (lane >> 4)) ^ (R & 7);
        af[im] = *(const bf16x8*)((const char*)As + R * 128 + s * 16);
      }
#pragma unroll
      for (int in_ = 0; in_ < 4; ++in_) {
        const int R = wc * 64 + in_ * 16 + (lane & 15);
        const int s = (kk * 4 + (lane >> 4)) ^ (R & 7);
        bfv[in_] = *(const bf16x8*)((const char*)Bs + R * 128 + s * 16);
      }
#pragma unroll
      for (int im = 0; im < 4; ++im)
#pragma unroll
        for (int in_ = 0; in_ < 4; ++in_)
          acc[im][in_] = MFMA16(af[im], bfv[in_], acc[im][in_], 0, 0, 0);
    }
    __syncthreads();
  }

  const int cn = lane & 15, cr4 = (lane >> 4) * 4;
#pragma unroll
  for (int im = 0; im < 4; ++im)
#pragma unroll
    for (int in_ = 0; in_ < 4; ++in_) {
      const int col = tn + wc * 64 + in_ * 16 + cn;
      const float bv = bias[col];
#pragma unroll
      for (int j = 0; j < 4; ++j) {
        const int row = tm + wr * 64 + im * 16 + cr4 + j;
        if (row < M)
          Cout[(size_t)row * ldc + col] = f2bf(gelu_fast(acc[im][in_][j] + bv));
      }
    }
}

// ---------------- candidate GEMM: per (n,r,row-half) 32x128 tile ----------------
__global__ __launch_bounds__(256, 4) void cand_gemm(
    const u16* __restrict__ hid, const u16* __restrict__ wao,
    const float* __restrict__ bout, const int* __restrict__ rstar,
    const float* __restrict__ wstar, float* __restrict__ out) {
  __shared__ u16 As[2][32 * 64];
  __shared__ u16 Bs[2][128 * 64];
  const int g = blockIdx.y, n = g >> 1, r = g & 1;
  const int src_a = (r == 0) ? (n >> 1) : (3 + (n & 1));
  const int dst_a = (r == 1) ? (n >> 1) : (3 + (n & 1));
  const int tn = blockIdx.x * 128;
  const int b0 = blockIdx.z * 32;
  const int tid = threadIdx.x, lane = tid & 63, wid = tid >> 6;
  const u16* Bbase = wao + (size_t)dst_a * 768 * 3072;
  const u16* Abase = hid + (size_t)src_a * 3072 + (size_t)n * 15360;

  f32x4 acc[2][2] = {};

  auto stage = [&](int buf, int t) {
    const int k0 = t << 6;
    {
      const int row = tid >> 3;  // 0..31
      const int sl  = (tid & 7) ^ (row & 7);
      async_load16(Abase + (size_t)(b0 + row) * 6 * 15360 + k0 + sl * 8,
                   (char*)As[buf] + row * 128 + (tid & 7) * 16);
    }
#pragma unroll
    for (int j = 0; j < 4; ++j) {
      const int row = j * 32 + (tid >> 3);  // 0..127
      const int sl  = (tid & 7) ^ (row & 7);
      async_load16(Bbase + (size_t)(tn + row) * 3072 + k0 + sl * 8,
                   (char*)Bs[buf] + row * 128 + (tid & 7) * 16);
    }
  };
  auto compute = [&](int buf) {
    const u16* as = As[buf];
    const u16* bs = Bs[buf];
#pragma unroll
    for (int kk = 0; kk < 2; ++kk) {
      bf16x8 af[2], bfv[2];
#pragma unroll
      for (int im = 0; im < 2; ++im) {
        const int R = im * 16 + (lane & 15);
        const int s = (kk * 4 + (lane >> 4)) ^ (R & 7);
        af[im] = *(const bf16x8*)(as + R * 64 + s * 8);
      }
#pragma unroll
      for (int q = 0; q < 2; ++q) {
        const int R = wid * 32 + q * 16 + (lane & 15);
        const int s = (kk * 4 + (lane >> 4)) ^ (R & 7);
        bfv[q] = *(const bf16x8*)(bs + R * 64 + s * 8);
      }
#pragma unroll
      for (int im = 0; im < 2; ++im)
#pragma unroll
        for (int q = 0; q < 2; ++q)
          acc[im][q] = MFMA16(af[im], bfv[q], acc[im][q], 0, 0, 0);
    }
  };

  stage(0, 0);
  __syncthreads();
  for (int t = 0; t < 48; ++t) {
    if (t + 1 < 48) stage((t + 1) & 1, t + 1);
    compute(t & 1);
    __syncthreads();
  }

  const int cn = lane & 15, cr4 = (lane >> 4) * 4;
#pragma unroll
  for (int im = 0; im < 2; ++im)
#pragma unroll
    for (int q = 0; q < 2; ++q) {
      const int col = tn + wid * 32 + q * 16 + cn;
      const float bv = bout[dst_a * 768 + col];
#pragma unroll
      for (int j = 0; j < 4; ++j) {
        const int b = b0 + im * 16 + cr4 + j;
        const int idx = b * 6 + n;
        if (rstar[idx] == r)
          out[((size_t)(b * 203 + n)) * 768 + col] = (acc[im][q][j] + bv) * wstar[idx];
      }
    }
}

// ---------------- launch ----------------
extern "C" void kernel_launch(void* const* d_in, const int* in_sizes, int n_in,
                              void* d_out, int out_size, void* d_ws, size_t ws_size,
                              hipStream_t stream) {
  const float* x     = (const float*)d_in[0];
  const float* fc1w  = (const float*)d_in[1];
  const float* fc1b  = (const float*)d_in[2];
  const float* fc2w  = (const float*)d_in[3];
  const float* fc2b  = (const float*)d_in[4];
  const float* gpair = (const float*)d_in[5];
  const float* aiw   = (const float*)d_in[6];
  const float* aib   = (const float*)d_in[7];
  const float* aow   = (const float*)d_in[8];
  const float* aob   = (const float*)d_in[9];
  const float* bbias = (const float*)d_in[10];
  float* out = (float*)d_out;

  char* ws = (char*)d_ws;
  u16* xp   = (u16*)(ws + 0);          // 12608x768 bf16
  u16* xc   = (u16*)(ws + 19365888);   // 384x768
  u16* w1   = (u16*)(ws + 19955712);   // 3072x768
  u16* w2   = (u16*)(ws + 24674304);   // 768x3072
  u16* wai  = (u16*)(ws + 29392896);   // 5x3072x768
  u16* wao  = (u16*)(ws + 52985856);   // 5x768x3072
  u16* hb   = (u16*)(ws + 76578816);   // 12608x3072
  u16* hid  = (u16*)(ws + 154042368);  // 384x15360
  int*   rstar = (int*)(ws + 165838848);
  float* wstar = (float*)(ws + 165840384);
  if (ws_size < 165841920) return;

  cvt_x2<<<dim3(203, 64), 192, 0, stream>>>(x, xc, xp);
  cvt_w<<<27648, 256, 0, stream>>>(fc1w, w1, fc2w, w2, aiw, wai, aow, wao);
  gate_kernel<<<96, 256, 0, stream>>>(x, gpair, bbias, rstar, wstar);
  // patch fc1 + gelu -> hb (bf16): 256x128 tiles, 8 waves
  gemm8w<0><<<dim3(24, 50), 512, 0, stream>>>(xp, w1, fc1b, hb, 12608, 768, 3072);
  // hid_all = gelu(cls @ atom_in_w^T + b): 128x128 tiles
  gemm4w<<<dim3(120, 3), 256, 0, stream>>>(xc, wai, aib, hid, 384, 768, 15360);
  // patch fc2 -> d_out (scatter): 256x128 tiles, 8 waves
  gemm8w<1><<<dim3(6, 50), 512, 0, stream>>>(hb, w2, fc2b, out, 12608, 3072, 768);
  // route candidates, chosen one written * prob
  cand_gemm<<<dim3(6, 12, 2), 256, 0, stream>>>(hid, wao, aob, rstar, wstar, out);
}

// Round 7
// 313.374 us; speedup vs baseline: 1.1964x; 1.0173x over previous
//
#include <hip/hip_runtime.h>
#include <hip/hip_bf16.h>

// Mlp_moe: patch MLP + 6-class 2-route MoE on cls tokens.
// Round 7: round-1 geometry (128^2, 4 waves, 2-barrier, single-buffer) with all GEMM
// addressing made loop-invariant: named staging pointers bumped +=64/tile, ds_read via
// 4 invariant bases + compile-time immediate offsets. Target: cut the 57% VALUBusy.

typedef __bf16 bf16x8 __attribute__((ext_vector_type(8)));
typedef float f32x4 __attribute__((ext_vector_type(4)));
typedef unsigned short u16;

#define DEVINL __device__ __forceinline__

DEVINL u16 f2bf(float f) {
  unsigned int u = __builtin_bit_cast(unsigned int, f);
  u += 0x7FFFu + ((u >> 16) & 1u);
  return (u16)(u >> 16);
}

// Winitzki erf: abs err ~2e-4 (vs bf16 rounding 0.008), branch-free.
DEVINL float gelu_fast(float v) {
  const float x2 = 0.5f * v * v;
  const float t = x2 * (1.27323954f + 0.147f * x2) / (1.0f + 0.147f * x2);
  const float r = sqrtf(fmaxf(1.0f - __expf(-t), 0.0f));
  const float e = copysignf(r, v);
  return 0.5f * v * (1.0f + e);
}

DEVINL void async_load16(const void* g, void* l) {
  __builtin_amdgcn_global_load_lds(
      (const __attribute__((address_space(1))) unsigned int*)g,
      (__attribute__((address_space(3))) unsigned int*)l, 16, 0, 0);
}

#define MFMA16 __builtin_amdgcn_mfma_f32_16x16x32_bf16

// ---------------- conversions ----------------
__global__ void cvt_x2(const float* __restrict__ x, u16* __restrict__ xc, u16* __restrict__ xp) {
  const int i = blockIdx.x, b = blockIdx.y;
  const int d = threadIdx.x * 4;
  const float4 v = *(const float4*)(x + ((size_t)(b * 203 + i)) * 768 + d);
  ushort4 u;
  u.x = f2bf(v.x); u.y = f2bf(v.y); u.z = f2bf(v.z); u.w = f2bf(v.w);
  if (i < 6) *(ushort4*)(xc + (size_t)(b * 6 + i) * 768 + d) = u;
  else       *(ushort4*)(xp + (size_t)(b * 197 + (i - 6)) * 768 + d) = u;
}

__global__ void cvt_w(const float* __restrict__ s1, u16* __restrict__ d1,
                      const float* __restrict__ s2, u16* __restrict__ d2,
                      const float* __restrict__ s3, u16* __restrict__ d3,
                      const float* __restrict__ s4, u16* __restrict__ d4) {
  int b = blockIdx.x;
  const float* s; u16* d;
  if (b < 2304) { s = s1; d = d1; }
  else if (b < 4608) { s = s2; d = d2; b -= 2304; }
  else if (b < 16128) { s = s3; d = d3; b -= 4608; }
  else { s = s4; d = d4; b -= 16128; }
  const int i = (b * 256 + threadIdx.x) * 4;
  const float4 v = *(const float4*)(s + i);
  ushort4 u;
  u.x = f2bf(v.x); u.y = f2bf(v.y); u.z = f2bf(v.z); u.w = f2bf(v.w);
  *(ushort4*)(d + i) = u;
}

// ---------------- gate / routing decision (fp64 accum) ----------------
__global__ void gate_kernel(const float* __restrict__ x,
                            const float* __restrict__ gate_pair,
                            const float* __restrict__ balance_bias,
                            int* __restrict__ rstar, float* __restrict__ wstar) {
  const int lane = threadIdx.x & 63, wid = threadIdx.x >> 6;
  const int idx = blockIdx.x * 4 + wid;
  const int b = idx / 6, n = idx % 6;
  const float* xv = x + (size_t)(b * 203 + n) * 768;
  const float* w0 = gate_pair + (size_t)(n * 2 + 0) * 768;
  const float* w1 = gate_pair + (size_t)(n * 2 + 1) * 768;
  double xx = 0, a00 = 0, a11 = 0, d0 = 0, d1 = 0;
  for (int d = lane; d < 768; d += 64) {
    double xd = xv[d], g0 = w0[d], g1 = w1[d];
    xx += xd * xd; a00 += g0 * g0; a11 += g1 * g1; d0 += xd * g0; d1 += xd * g1;
  }
#pragma unroll
  for (int off = 32; off; off >>= 1) {
    xx  += __shfl_xor(xx, off);
    a00 += __shfl_xor(a00, off);
    a11 += __shfl_xor(a11, off);
    d0  += __shfl_xor(d0, off);
    d1  += __shfl_xor(d1, off);
  }
  if (lane == 0) {
    double nx = fmax(sqrt(xx), 1e-12), n0 = fmax(sqrt(a00), 1e-12), n1 = fmax(sqrt(a11), 1e-12);
    double l0 = d0 / (nx * n0) + (double)balance_bias[n * 2 + 0];
    double l1 = d1 / (nx * n1) + (double)balance_bias[n * 2 + 1];
    const int r = (l1 > l0) ? 1 : 0;
    double m = fmax(l0, l1);
    double e0 = exp(l0 - m), e1 = exp(l1 - m);
    rstar[idx] = r;
    wstar[idx] = (float)(((r == 1) ? e1 : e0) / (e0 + e1));
  }
}

// ---------------- 128x128 4-wave GEMM, loop-invariant addressing ----------------
// C = A(MxK) * B(NxK)^T + bias. Slot swizzle ^(row&7) both sides.
// Staging: 8 named pointers += 64 elems/tile; LDS dests = 2 bases + imm offsets
// (wave-uniform base + lane*16 preserved). ds_read: 4 invariant bases + im*2048 imms.
template <int EPI>
__global__ __launch_bounds__(256, 2) void gemm_bt(
    const u16* __restrict__ A, const u16* __restrict__ B,
    const float* __restrict__ bias, void* __restrict__ Cout,
    int M, int K, int ldc) {
  __shared__ u16 As[128 * 64];
  __shared__ u16 Bs[128 * 64];
  const int tid = threadIdx.x;
  const int lane = tid & 63, wid = tid >> 6;
  const int wr = wid >> 1, wc = wid & 1;
  const int tm = blockIdx.y * 128, tn = blockIdx.x * 128;
  const int ksteps = K >> 6;

  // staging addressing (loop-invariant)
  const int srow = tid >> 3;          // 0..31
  const int ss   = tid & 7;           // dest slot
  const int sl   = ss ^ (srow & 7);   // inverse-swizzled source slot (j*32 preserves row&7)
  char* ldsA = (char*)As + srow * 128 + ss * 16;
  char* ldsB = (char*)Bs + srow * 128 + ss * 16;
  int g0 = tm + srow,      c0 = g0 < M ? g0 : M - 1;
  int g1 = tm + 32 + srow, c1 = g1 < M ? g1 : M - 1;
  int g2 = tm + 64 + srow, c2 = g2 < M ? g2 : M - 1;
  int g3 = tm + 96 + srow, c3 = g3 < M ? g3 : M - 1;
  const u16* pA0 = A + (size_t)c0 * K + sl * 8;
  const u16* pA1 = A + (size_t)c1 * K + sl * 8;
  const u16* pA2 = A + (size_t)c2 * K + sl * 8;
  const u16* pA3 = A + (size_t)c3 * K + sl * 8;
  const u16* pB0 = B + (size_t)(tn + srow) * K + sl * 8;
  const u16* pB1 = B + (size_t)(tn + 32 + srow) * K + sl * 8;
  const u16* pB2 = B + (size_t)(tn + 64 + srow) * K + sl * 8;
  const u16* pB3 = B + (size_t)(tn + 96 + srow) * K + sl * 8;

  // compute-read addressing (loop-invariant bases; slot XOR is row-independent)
  const int x7 = lane & 7, hi = lane >> 4, l15 = lane & 15;
  const char* rdA0 = (const char*)As + (wr * 64 + l15) * 128 + ((0 + hi) ^ x7) * 16;
  const char* rdA1 = (const char*)As + (wr * 64 + l15) * 128 + ((4 + hi) ^ x7) * 16;
  const char* rdB0 = (const char*)Bs + (wc * 64 + l15) * 128 + ((0 + hi) ^ x7) * 16;
  const char* rdB1 = (const char*)Bs + (wc * 64 + l15) * 128 + ((4 + hi) ^ x7) * 16;

  f32x4 acc[4][4] = {};

  for (int t = 0; t < ksteps; ++t) {
    async_load16(pA0, ldsA);
    async_load16(pA1, ldsA + 4096);
    async_load16(pA2, ldsA + 8192);
    async_load16(pA3, ldsA + 12288);
    async_load16(pB0, ldsB);
    async_load16(pB1, ldsB + 4096);
    async_load16(pB2, ldsB + 8192);
    async_load16(pB3, ldsB + 12288);
    pA0 += 64; pA1 += 64; pA2 += 64; pA3 += 64;
    pB0 += 64; pB1 += 64; pB2 += 64; pB3 += 64;
    __syncthreads();  // vmcnt(0) drain: staged data visible
#pragma unroll
    for (int kk = 0; kk < 2; ++kk) {
      const char* ra = kk ? rdA1 : rdA0;
      const char* rb = kk ? rdB1 : rdB0;
      bf16x8 af[4], bfv[4];
#pragma unroll
      for (int im = 0; im < 4; ++im) af[im] = *(const bf16x8*)(ra + im * 2048);
#pragma unroll
      for (int in_ = 0; in_ < 4; ++in_) bfv[in_] = *(const bf16x8*)(rb + in_ * 2048);
#pragma unroll
      for (int im = 0; im < 4; ++im)
#pragma unroll
        for (int in_ = 0; in_ < 4; ++in_)
          acc[im][in_] = MFMA16(af[im], bfv[in_], acc[im][in_], 0, 0, 0);
    }
    __syncthreads();  // protect single buffer
  }

  const int cn = lane & 15, cr4 = (lane >> 4) * 4;
#pragma unroll
  for (int im = 0; im < 4; ++im) {
#pragma unroll
    for (int in_ = 0; in_ < 4; ++in_) {
      const int col = tn + wc * 64 + in_ * 16 + cn;
      const float bv = bias[col];
#pragma unroll
      for (int j = 0; j < 4; ++j) {
        const int row = tm + wr * 64 + im * 16 + cr4 + j;
        if (row < M) {
          const float v = acc[im][in_][j] + bv;
          if (EPI == 0) {
            ((u16*)Cout)[(size_t)row * ldc + col] = f2bf(gelu_fast(v));
          } else {
            const int b = row / 197, pp = row % 197;
            ((float*)Cout)[((size_t)(b * 203 + 6 + pp)) * 768 + col] = v;
          }
        }
      }
    }
  }
}

// ---------------- candidate GEMM: per (n,r,row-half) 32x128 tile ----------------
__global__ __launch_bounds__(256, 4) void cand_gemm(
    const u16* __restrict__ hid, const u16* __restrict__ wao,
    const float* __restrict__ bout, const int* __restrict__ rstar,
    const float* __restrict__ wstar, float* __restrict__ out) {
  __shared__ u16 As[2][32 * 64];
  __shared__ u16 Bs[2][128 * 64];
  const int g = blockIdx.y, n = g >> 1, r = g & 1;
  const int src_a = (r == 0) ? (n >> 1) : (3 + (n & 1));
  const int dst_a = (r == 1) ? (n >> 1) : (3 + (n & 1));
  const int tn = blockIdx.x * 128;
  const int b0 = blockIdx.z * 32;
  const int tid = threadIdx.x, lane = tid & 63, wid = tid >> 6;
  const u16* Bbase = wao + (size_t)dst_a * 768 * 3072;
  const u16* Abase = hid + (size_t)src_a * 3072 + (size_t)n * 15360;

  f32x4 acc[2][2] = {};

  auto stage = [&](int buf, int t) {
    const int k0 = t << 6;
    {
      const int row = tid >> 3;  // 0..31
      const int slA = (tid & 7) ^ (row & 7);
      async_load16(Abase + (size_t)(b0 + row) * 6 * 15360 + k0 + slA * 8,
                   (char*)As[buf] + row * 128 + (tid & 7) * 16);
    }
#pragma unroll
    for (int j = 0; j < 4; ++j) {
      const int row = j * 32 + (tid >> 3);  // 0..127
      const int slB = (tid & 7) ^ (row & 7);
      async_load16(Bbase + (size_t)(tn + row) * 3072 + k0 + slB * 8,
                   (char*)Bs[buf] + row * 128 + (tid & 7) * 16);
    }
  };
  auto compute = [&](int buf) {
    const u16* as = As[buf];
    const u16* bs = Bs[buf];
#pragma unroll
    for (int kk = 0; kk < 2; ++kk) {
      bf16x8 af[2], bfv[2];
#pragma unroll
      for (int im = 0; im < 2; ++im) {
        const int R = im * 16 + (lane & 15);
        const int s = (kk * 4 + (lane >> 4)) ^ (R & 7);
        af[im] = *(const bf16x8*)(as + R * 64 + s * 8);
      }
#pragma unroll
      for (int q = 0; q < 2; ++q) {
        const int R = wid * 32 + q * 16 + (lane & 15);
        const int s = (kk * 4 + (lane >> 4)) ^ (R & 7);
        bfv[q] = *(const bf16x8*)(bs + R * 64 + s * 8);
      }
#pragma unroll
      for (int im = 0; im < 2; ++im)
#pragma unroll
        for (int q = 0; q < 2; ++q)
          acc[im][q] = MFMA16(af[im], bfv[q], acc[im][q], 0, 0, 0);
    }
  };

  stage(0, 0);
  __syncthreads();
  for (int t = 0; t < 48; ++t) {
    if (t + 1 < 48) stage((t + 1) & 1, t + 1);
    compute(t & 1);
    __syncthreads();
  }

  const int cn = lane & 15, cr4 = (lane >> 4) * 4;
#pragma unroll
  for (int im = 0; im < 2; ++im)
#pragma unroll
    for (int q = 0; q < 2; ++q) {
      const int col = tn + wid * 32 + q * 16 + cn;
      const float bv = bout[dst_a * 768 + col];
#pragma unroll
      for (int j = 0; j < 4; ++j) {
        const int b = b0 + im * 16 + cr4 + j;
        const int idx = b * 6 + n;
        if (rstar[idx] == r)
          out[((size_t)(b * 203 + n)) * 768 + col] = (acc[im][q][j] + bv) * wstar[idx];
      }
    }
}

// ---------------- launch ----------------
extern "C" void kernel_launch(void* const* d_in, const int* in_sizes, int n_in,
                              void* d_out, int out_size, void* d_ws, size_t ws_size,
                              hipStream_t stream) {
  const float* x     = (const float*)d_in[0];
  const float* fc1w  = (const float*)d_in[1];
  const float* fc1b  = (const float*)d_in[2];
  const float* fc2w  = (const float*)d_in[3];
  const float* fc2b  = (const float*)d_in[4];
  const float* gpair = (const float*)d_in[5];
  const float* aiw   = (const float*)d_in[6];
  const float* aib   = (const float*)d_in[7];
  const float* aow   = (const float*)d_in[8];
  const float* aob   = (const float*)d_in[9];
  const float* bbias = (const float*)d_in[10];
  float* out = (float*)d_out;

  char* ws = (char*)d_ws;
  u16* xp   = (u16*)(ws + 0);          // 12608x768 bf16
  u16* xc   = (u16*)(ws + 19365888);   // 384x768
  u16* w1   = (u16*)(ws + 19955712);   // 3072x768
  u16* w2   = (u16*)(ws + 24674304);   // 768x3072
  u16* wai  = (u16*)(ws + 29392896);   // 5x3072x768
  u16* wao  = (u16*)(ws + 52985856);   // 5x768x3072
  u16* hb   = (u16*)(ws + 76578816);   // 12608x3072
  u16* hid  = (u16*)(ws + 154042368);  // 384x15360
  int*   rstar = (int*)(ws + 165838848);
  float* wstar = (float*)(ws + 165840384);
  if (ws_size < 165841920) return;

  cvt_x2<<<dim3(203, 64), 192, 0, stream>>>(x, xc, xp);
  cvt_w<<<27648, 256, 0, stream>>>(fc1w, w1, fc2w, w2, aiw, wai, aow, wao);
  gate_kernel<<<96, 256, 0, stream>>>(x, gpair, bbias, rstar, wstar);
  // patch fc1 + gelu -> hb (bf16)
  gemm_bt<0><<<dim3(24, 99), 256, 0, stream>>>(xp, w1, fc1b, hb, 12608, 768, 3072);
  // hid_all = gelu(cls @ atom_in_w^T + b) for all 5 atoms
  gemm_bt<0><<<dim3(120, 3), 256, 0, stream>>>(xc, wai, aib, hid, 384, 768, 15360);
  // patch fc2 -> d_out (scatter to b*203+6+p rows)
  gemm_bt<1><<<dim3(6, 99), 256, 0, stream>>>(hb, w2, fc2b, out, 12608, 3072, 768);
  // route candidates, chosen one written * prob
  cand_gemm<<<dim3(6, 12, 2), 256, 0, stream>>>(hid, wao, aob, rstar, wstar, out);
}